// Round 6
// baseline (915.938 us; speedup 1.0000x reference)
//
#include <hip/hip_runtime.h>
#include <math.h>

// Problem constants (match reference)
#define B_   16
#define T_   1024
#define F_   512
#define G_   2
#define V_   320
#define D_   128
#define N_   (B_ * T_)      // 16384 tokens
#define GV   (G_ * V_)      // 640
#define EPS_ 1e-7f

// Kernel config
#define ROWS    32          // rows per block
#define THREADS 256         // 4 waves; wave wv owns rows wv*8..wv*8+7
#define KC      16          // k-chunk staged in LDS
#define WSTRIDE 20          // padded LDS row stride (floats); uniform bank coverage
#define NBLK    (N_ / ROWS) // 512 blocks -> 2 blocks/CU, grid fully resident
#define NCHUNK  (F_ / KC)   // 32

// Workspace layout (floats)
#define WS_COUNTS 0                        // T_*G_*V_ = 655360 (zeroed each launch)
#define WS_AVG    (T_ * G_ * V_)           // NBLK*GV  = 327680
#define WS_ENT    (WS_AVG + NBLK * GV)     // T_*G_    = 2048
// avgred (GV floats) reuses counts[0:GV] after k_stats consumed counts.

#define FMA4(a, xv, wv_)                                                       \
  a = fmaf(xv.x, wv_.x, a); a = fmaf(xv.y, wv_.y, a);                          \
  a = fmaf(xv.z, wv_.z, a); a = fmaf(xv.w, wv_.w, a);

// Fused: GEMM (x @ w^T + b) + softmax stats + argmaxes + codebook gather.
// w/x k-slabs staged via registers (double-buffered) into padded LDS.
// waves_per_eu(2,2): pin allocator to the full 256-VGPR budget — R5's
// heuristic squeeze to 128 VGPR spilled the 147-reg live set in the hot loop.
__global__ __attribute__((amdgpu_waves_per_eu(2, 2))) __launch_bounds__(THREADS)
void k_fused(
    const float* __restrict__ x, const float* __restrict__ w,
    const float* __restrict__ bias, const float* __restrict__ cb,
    const float* __restrict__ gum, float* __restrict__ out,
    float* __restrict__ counts, float* __restrict__ avg_part)
{
  __shared__ float lw[GV][WSTRIDE];    // 50 KB   w k-slab, padded
  __shared__ float lx[ROWS][WSTRIDE];  // 2.5 KB  x k-slab, padded
  const int tid = threadIdx.x;
  const int wv  = tid >> 6;   // wave / row-group 0..3
  const int ln  = tid & 63;
  const int blk = blockIdx.x;
  const int n0  = blk * ROWS;
  const int r0  = wv * 8;

  float acc[G_][5][8];
#pragma unroll
  for (int g = 0; g < G_; ++g)
#pragma unroll
    for (int j = 0; j < 5; ++j)
#pragma unroll
      for (int r = 0; r < 8; ++r) acc[g][j][r] = 0.f;

  const float4* w4 = (const float4*)w;
  const float4* x4 = (const float4*)x;

  // staging thread mapping: thread -> (row tid/4 + 64*it, quad tid%4)
  const int srow = tid >> 2, squad = tid & 3;

  // ---- prefetch chunk 0 into registers ----
  float4 wbuf[10];
  float4 xbuf;
#pragma unroll
  for (int it = 0; it < 10; ++it)
    wbuf[it] = w4[(size_t)(srow + 64 * it) * (F_ / 4) + squad];
  if (tid < ROWS * 4)
    xbuf = x4[(size_t)(n0 + srow) * (F_ / 4) + squad];

  for (int c = 0; c < NCHUNK; ++c) {
    __syncthreads();  // chunk c-1 consumers done
    // regs -> LDS
#pragma unroll
    for (int it = 0; it < 10; ++it)
      *(float4*)&lw[srow + 64 * it][squad * 4] = wbuf[it];
    if (tid < ROWS * 4)
      *(float4*)&lx[srow][squad * 4] = xbuf;
    // issue prefetch for chunk c+1 (in flight during compute below)
    if (c + 1 < NCHUNK) {
#pragma unroll
      for (int it = 0; it < 10; ++it)
        wbuf[it] = w4[(size_t)(srow + 64 * it) * (F_ / 4) + (c + 1) * 4 + squad];
      if (tid < ROWS * 4)
        xbuf = x4[(size_t)(n0 + srow) * (F_ / 4) + (c + 1) * 4 + squad];
    }
    __syncthreads();  // LDS ready

#pragma unroll
    for (int kk = 0; kk < 4; ++kk) {
      float4 xreg[8];
#pragma unroll
      for (int r = 0; r < 8; ++r)
        xreg[r] = *(const float4*)&lx[r0 + r][kk * 4];  // wave-uniform broadcast
#pragma unroll
      for (int g = 0; g < G_; ++g) {
        float4 wreg[5];
#pragma unroll
        for (int j = 0; j < 5; ++j)
          wreg[j] = *(const float4*)&lw[g * V_ + 64 * j + ln][kk * 4];
#pragma unroll
        for (int j = 0; j < 5; ++j)
#pragma unroll
          for (int r = 0; r < 8; ++r) { FMA4(acc[g][j][r], xreg[r], wreg[j]); }
      }
    }
  }

  // ---- phase 2: per-row softmax / argmax / gather, all from registers ----
  float bs[G_][5];
#pragma unroll
  for (int g = 0; g < G_; ++g)
#pragma unroll
    for (int j = 0; j < 5; ++j) bs[g][j] = bias[g * V_ + 64 * j + ln];

  float racc[G_][5];
#pragma unroll
  for (int g = 0; g < G_; ++g)
#pragma unroll
    for (int j = 0; j < 5; ++j) racc[g][j] = 0.f;

#pragma unroll
  for (int r = 0; r < 8; ++r) {
    const int n = n0 + r0 + r;
#pragma unroll
    for (int g = 0; g < G_; ++g) {
      float L[5], GU[5];
#pragma unroll
      for (int j = 0; j < 5; ++j) {
        L[j]  = acc[g][j][r] + bs[g][j];
        GU[j] = gum[(size_t)n * GV + g * V_ + 64 * j + ln];
      }
      // local max/argmax (cols ascend with j -> first-occurrence tie-break)
      float m1 = L[0];         int a1 = ln;
      float m2 = L[0] + GU[0]; int a2 = ln;
#pragma unroll
      for (int j = 1; j < 5; ++j) {
        const int cix = 64 * j + ln;
        if (L[j] > m1) { m1 = L[j]; a1 = cix; }
        const float t2 = L[j] + GU[j];
        if (t2 > m2) { m2 = t2; a2 = cix; }
      }
      // wave reduce (prefer smaller index on exact ties)
      for (int off = 32; off; off >>= 1) {
        float om = __shfl_down(m1, off); int oa = __shfl_down(a1, off);
        if (om > m1 || (om == m1 && oa < a1)) { m1 = om; a1 = oa; }
        float om2 = __shfl_down(m2, off); int oa2 = __shfl_down(a2, off);
        if (om2 > m2 || (om2 == m2 && oa2 < a2)) { m2 = om2; a2 = oa2; }
      }
      m1 = __shfl(m1, 0); a1 = __shfl(a1, 0); a2 = __shfl(a2, 0);

      // softmax (no tau) for avg_probs
      float e[5], s = 0.f;
#pragma unroll
      for (int j = 0; j < 5; ++j) { e[j] = expf(L[j] - m1); s += e[j]; }
      for (int off = 32; off; off >>= 1) s += __shfl_down(s, off);
      s = __shfl(s, 0);
      const float inv = 1.0f / s;
#pragma unroll
      for (int j = 0; j < 5; ++j) racc[g][j] += e[j] * inv;

      if (ln == 0) {
        const int t = n & (T_ - 1);
        atomicAdd(&counts[(t * G_ + g) * V_ + a1], 1.0f);
      }
      // quantized[n, g*D : (g+1)*D] = codebook[g, a2, :]
      const float2* cbr = (const float2*)(cb + (size_t)(g * V_ + a2) * D_);
      float2* op = (float2*)(out + (size_t)n * (G_ * D_) + g * D_);
      op[ln] = cbr[ln];
    }
  }

  // ---- block-level avg_probs partial: reduce 4 wave-private copies ----
  __syncthreads();
  float* la = (float*)lw;  // [4][GV]: 10240 floats <= 640*20
#pragma unroll
  for (int g = 0; g < G_; ++g)
#pragma unroll
    for (int j = 0; j < 5; ++j)
      la[wv * GV + g * V_ + 64 * j + ln] = racc[g][j];
  __syncthreads();
  for (int cix = tid; cix < GV; cix += THREADS) {
    float s = 0.f;
#pragma unroll
    for (int v = 0; v < 4; ++v) s += la[v * GV + cix];
    avg_part[(size_t)blk * GV + cix] = s;
  }
}

// Merged stats kernel:
//  blocks [0, 512): per-(t,g) hard-histogram entropy -> exp(-H), 4 items/block
//  blocks [512, 672): column-reduce avg_part (512 x 640) -> avgred, 4 cols/block
__global__ __launch_bounds__(256) void k_stats(
    const float* __restrict__ counts, const float* __restrict__ avg_part,
    float* __restrict__ ent, float* __restrict__ avgred)
{
  const int wave = threadIdx.x >> 6;
  const int lane = threadIdx.x & 63;
  if (blockIdx.x < 512) {
    const int item = blockIdx.x * 4 + wave;  // 0..2047
    const float* c = counts + (size_t)item * V_;
    float s = 0.f;
#pragma unroll
    for (int j = 0; j < 5; ++j) {
      const float hp = c[lane + 64 * j] * (1.0f / B_);
      s += hp * logf(hp + EPS_);
    }
    for (int off = 32; off; off >>= 1) s += __shfl_down(s, off);
    if (lane == 0) ent[item] = expf(-s);
  } else {
    const int cix = (blockIdx.x - 512) * 4 + wave;  // 0..639
    float s = 0.f;
    for (int b = lane; b < NBLK; b += 64) s += avg_part[(size_t)b * GV + cix];
    for (int off = 32; off; off >>= 1) s += __shfl_down(s, off);
    if (lane == 0) avgred[cix] = s;
  }
}

// Finalize both scalars. Single block of 640 threads.
__global__ __launch_bounds__(GV) void k_final(
    const float* __restrict__ avgred, const float* __restrict__ ent,
    float* __restrict__ out2)
{
  __shared__ float sh[GV];   // p*log(p+eps) per column
  __shared__ float shc[GV];  // code-entropy partials
  const int tid = threadIdx.x;

  const float p = avgred[tid] * (1.0f / N_);
  sh[tid] = p * logf(p + EPS_);

  float cs = 0.f;
  for (int i = tid; i < T_ * G_; i += GV) cs += ent[i];
  shc[tid] = cs;
  __syncthreads();

  if (tid < 64) {
    float s0 = 0.f, s1 = 0.f, sc = 0.f;
    for (int j = tid; j < V_; j += 64) { s0 += sh[j]; s1 += sh[V_ + j]; }
    for (int j = tid; j < GV; j += 64) sc += shc[j];
    for (int off = 32; off; off >>= 1) {
      s0 += __shfl_down(s0, off);
      s1 += __shfl_down(s1, off);
      sc += __shfl_down(sc, off);
    }
    if (tid == 0) {
      out2[0] = sc;                          // code_perplexity
      out2[1] = expf(-s0) + expf(-s1);       // prob_perplexity
    }
  }
}

extern "C" void kernel_launch(void* const* d_in, const int* in_sizes, int n_in,
                              void* d_out, int out_size, void* d_ws, size_t ws_size,
                              hipStream_t stream) {
  const float* x   = (const float*)d_in[0];  // (B,T,F)
  const float* w   = (const float*)d_in[1];  // (G*V, F)
  const float* b   = (const float*)d_in[2];  // (G*V,)
  const float* cb  = (const float*)d_in[3];  // (1, G*V, D)
  const float* gum = (const float*)d_in[4];  // (B*T, G, V)
  float* out = (float*)d_out;                // quantized (N*G*D) ++ [code_ppl, prob_ppl]
  float* ws  = (float*)d_ws;

  float* counts = ws + WS_COUNTS;
  float* avgp   = ws + WS_AVG;
  float* ent    = ws + WS_ENT;
  float* avgred = counts;  // reuse: counts is dead after k_stats (stream-ordered)

  hipMemsetAsync(counts, 0, (size_t)T_ * G_ * V_ * sizeof(float), stream);
  k_fused<<<NBLK, THREADS, 0, stream>>>(x, w, b, cb, gum, out, counts, avgp);
  k_stats<<<512 + GV / 4, 256, 0, stream>>>(counts, avgp, ent, avgred);
  k_final<<<1, GV, 0, stream>>>(avgred, ent, out + (size_t)N_ * G_ * D_);
}

// Round 7
// 490.344 us; speedup vs baseline: 1.8680x; 1.8680x over previous
//
#include <hip/hip_runtime.h>
#include <math.h>

// Problem constants (match reference)
#define B_   16
#define T_   1024
#define F_   512
#define G_   2
#define V_   320
#define D_   128
#define N_   (B_ * T_)      // 16384 tokens
#define GV   (G_ * V_)      // 640
#define EPS_ 1e-7f

// Kernel config
#define ROWS    32          // rows per block
#define THREADS 256         // 4 waves; wave wv owns rows wv*8..wv*8+7
#define KC      16          // k-chunk staged in LDS
#define WSTRIDE 20          // padded LDS row stride (floats): 80B = 5 granules -> b128 conflict-free
#define NBLK    (N_ / ROWS) // 512 blocks -> 2 blocks/CU, grid fully resident
#define NCHUNK  (F_ / KC)   // 32

// Workspace layout (floats)
#define WS_COUNTS 0                        // T_*G_*V_ = 655360 (zeroed each launch)
#define WS_AVG    (T_ * G_ * V_)           // NBLK*GV  = 327680
#define WS_ENT    (WS_AVG + NBLK * GV)     // T_*G_    = 2048
// avgred (GV floats) reuses counts[0:GV] after k_stats consumed counts.

#define FMA4(a, xv, wv_)                                                       \
  a = fmaf(xv.x, wv_.x, a); a = fmaf(xv.y, wv_.y, a);                          \
  a = fmaf(xv.z, wv_.z, a); a = fmaf(xv.w, wv_.w, a);

// Fused: GEMM (x @ w^T + b) + softmax stats + argmaxes + codebook gather.
// amdgpu_num_vgpr(208): R5/R6 showed the allocator's heuristic pins 128 VGPR
// (ignoring the LDS-capped 2-blocks/CU occupancy) -> reg-dbuf spilled to
// scratch (R6: 3 GB HBM spill traffic). 208 covers the ~191-reg live set;
// 2x208 <= 512/SIMD keeps 2 waves/EU.
// Prefetch for chunk c+1 issues AFTER the second barrier (compiler drains
// vmcnt(0) at every s_barrier), so loads fly during the 1280-FMA compute.
__global__ __attribute__((amdgpu_num_vgpr(208))) __launch_bounds__(THREADS)
void k_fused(
    const float* __restrict__ x, const float* __restrict__ w,
    const float* __restrict__ bias, const float* __restrict__ cb,
    const float* __restrict__ gum, float* __restrict__ out,
    float* __restrict__ counts, float* __restrict__ avg_part)
{
  __shared__ float lw[GV][WSTRIDE];    // 50 KB   w k-slab, padded
  __shared__ float lx[ROWS][WSTRIDE];  // 2.5 KB  x k-slab, padded
  const int tid = threadIdx.x;
  const int wv  = tid >> 6;   // wave / row-group 0..3
  const int ln  = tid & 63;
  const int blk = blockIdx.x;
  const int n0  = blk * ROWS;
  const int r0  = wv * 8;

  float acc[G_][5][8];
#pragma unroll
  for (int g = 0; g < G_; ++g)
#pragma unroll
    for (int j = 0; j < 5; ++j)
#pragma unroll
      for (int r = 0; r < 8; ++r) acc[g][j][r] = 0.f;

  const float4* w4 = (const float4*)w;
  const float4* x4 = (const float4*)x;

  // staging thread mapping: thread -> (row tid/4 + 64*it, quad tid%4)
  const int srow = tid >> 2, squad = tid & 3;

  // ---- prefetch chunk 0 into registers ----
  float4 wbuf[10];
  float4 xbuf;
#pragma unroll
  for (int it = 0; it < 10; ++it)
    wbuf[it] = w4[(size_t)(srow + 64 * it) * (F_ / 4) + squad];
  if (tid < ROWS * 4)
    xbuf = x4[(size_t)(n0 + srow) * (F_ / 4) + squad];

  for (int c = 0; c < NCHUNK; ++c) {
    __syncthreads();  // (a) chunk c-1 consumers done; prefetch loads long done
    // regs -> LDS
#pragma unroll
    for (int it = 0; it < 10; ++it)
      *(float4*)&lw[srow + 64 * it][squad * 4] = wbuf[it];
    if (tid < ROWS * 4)
      *(float4*)&lx[srow][squad * 4] = xbuf;
    __syncthreads();  // (b) LDS ready

    // issue prefetch for chunk c+1 NOW (post-barrier) -> in flight during FMAs
    if (c + 1 < NCHUNK) {
#pragma unroll
      for (int it = 0; it < 10; ++it)
        wbuf[it] = w4[(size_t)(srow + 64 * it) * (F_ / 4) + (c + 1) * 4 + squad];
      if (tid < ROWS * 4)
        xbuf = x4[(size_t)(n0 + srow) * (F_ / 4) + (c + 1) * 4 + squad];
    }

#pragma unroll
    for (int kk = 0; kk < 4; ++kk) {
      float4 xreg[8];
#pragma unroll
      for (int r = 0; r < 8; ++r)
        xreg[r] = *(const float4*)&lx[r0 + r][kk * 4];  // wave-uniform broadcast
#pragma unroll
      for (int g = 0; g < G_; ++g) {
        float4 wreg[5];
#pragma unroll
        for (int j = 0; j < 5; ++j)
          wreg[j] = *(const float4*)&lw[g * V_ + 64 * j + ln][kk * 4];
#pragma unroll
        for (int j = 0; j < 5; ++j)
#pragma unroll
          for (int r = 0; r < 8; ++r) { FMA4(acc[g][j][r], xreg[r], wreg[j]); }
      }
    }
  }

  // ---- phase 2: per-row softmax / argmax / gather, all from registers ----
  float bs[G_][5];
#pragma unroll
  for (int g = 0; g < G_; ++g)
#pragma unroll
    for (int j = 0; j < 5; ++j) bs[g][j] = bias[g * V_ + 64 * j + ln];

  float racc[G_][5];
#pragma unroll
  for (int g = 0; g < G_; ++g)
#pragma unroll
    for (int j = 0; j < 5; ++j) racc[g][j] = 0.f;

#pragma unroll
  for (int r = 0; r < 8; ++r) {
    const int n = n0 + r0 + r;
#pragma unroll
    for (int g = 0; g < G_; ++g) {
      float L[5], GU[5];
#pragma unroll
      for (int j = 0; j < 5; ++j) {
        L[j]  = acc[g][j][r] + bs[g][j];
        GU[j] = gum[(size_t)n * GV + g * V_ + 64 * j + ln];
      }
      // local max/argmax (cols ascend with j -> first-occurrence tie-break)
      float m1 = L[0];         int a1 = ln;
      float m2 = L[0] + GU[0]; int a2 = ln;
#pragma unroll
      for (int j = 1; j < 5; ++j) {
        const int cix = 64 * j + ln;
        if (L[j] > m1) { m1 = L[j]; a1 = cix; }
        const float t2 = L[j] + GU[j];
        if (t2 > m2) { m2 = t2; a2 = cix; }
      }
      // wave reduce (prefer smaller index on exact ties)
      for (int off = 32; off; off >>= 1) {
        float om = __shfl_down(m1, off); int oa = __shfl_down(a1, off);
        if (om > m1 || (om == m1 && oa < a1)) { m1 = om; a1 = oa; }
        float om2 = __shfl_down(m2, off); int oa2 = __shfl_down(a2, off);
        if (om2 > m2 || (om2 == m2 && oa2 < a2)) { m2 = om2; a2 = oa2; }
      }
      m1 = __shfl(m1, 0); a1 = __shfl(a1, 0); a2 = __shfl(a2, 0);

      // softmax (no tau) for avg_probs
      float e[5], s = 0.f;
#pragma unroll
      for (int j = 0; j < 5; ++j) { e[j] = expf(L[j] - m1); s += e[j]; }
      for (int off = 32; off; off >>= 1) s += __shfl_down(s, off);
      s = __shfl(s, 0);
      const float inv = 1.0f / s;
#pragma unroll
      for (int j = 0; j < 5; ++j) racc[g][j] += e[j] * inv;

      if (ln == 0) {
        const int t = n & (T_ - 1);
        atomicAdd(&counts[(t * G_ + g) * V_ + a1], 1.0f);
      }
      // quantized[n, g*D : (g+1)*D] = codebook[g, a2, :]
      const float2* cbr = (const float2*)(cb + (size_t)(g * V_ + a2) * D_);
      float2* op = (float2*)(out + (size_t)n * (G_ * D_) + g * D_);
      op[ln] = cbr[ln];
    }
  }

  // ---- block-level avg_probs partial: reduce 4 wave-private copies ----
  __syncthreads();
  float* la = (float*)lw;  // [4][GV]: 10240 floats <= 640*20
#pragma unroll
  for (int g = 0; g < G_; ++g)
#pragma unroll
    for (int j = 0; j < 5; ++j)
      la[wv * GV + g * V_ + 64 * j + ln] = racc[g][j];
  __syncthreads();
  for (int cix = tid; cix < GV; cix += THREADS) {
    float s = 0.f;
#pragma unroll
    for (int v = 0; v < 4; ++v) s += la[v * GV + cix];
    avg_part[(size_t)blk * GV + cix] = s;
  }
}

// Merged stats kernel:
//  blocks [0, 512): per-(t,g) hard-histogram entropy -> exp(-H), 4 items/block
//  blocks [512, 672): column-reduce avg_part (512 x 640) -> avgred, 4 cols/block
__global__ __launch_bounds__(256) void k_stats(
    const float* __restrict__ counts, const float* __restrict__ avg_part,
    float* __restrict__ ent, float* __restrict__ avgred)
{
  const int wave = threadIdx.x >> 6;
  const int lane = threadIdx.x & 63;
  if (blockIdx.x < 512) {
    const int item = blockIdx.x * 4 + wave;  // 0..2047
    const float* c = counts + (size_t)item * V_;
    float s = 0.f;
#pragma unroll
    for (int j = 0; j < 5; ++j) {
      const float hp = c[lane + 64 * j] * (1.0f / B_);
      s += hp * logf(hp + EPS_);
    }
    for (int off = 32; off; off >>= 1) s += __shfl_down(s, off);
    if (lane == 0) ent[item] = expf(-s);
  } else {
    const int cix = (blockIdx.x - 512) * 4 + wave;  // 0..639
    float s = 0.f;
    for (int b = lane; b < NBLK; b += 64) s += avg_part[(size_t)b * GV + cix];
    for (int off = 32; off; off >>= 1) s += __shfl_down(s, off);
    if (lane == 0) avgred[cix] = s;
  }
}

// Finalize both scalars. Single block of 640 threads.
__global__ __launch_bounds__(GV) void k_final(
    const float* __restrict__ avgred, const float* __restrict__ ent,
    float* __restrict__ out2)
{
  __shared__ float sh[GV];   // p*log(p+eps) per column
  __shared__ float shc[GV];  // code-entropy partials
  const int tid = threadIdx.x;

  const float p = avgred[tid] * (1.0f / N_);
  sh[tid] = p * logf(p + EPS_);

  float cs = 0.f;
  for (int i = tid; i < T_ * G_; i += GV) cs += ent[i];
  shc[tid] = cs;
  __syncthreads();

  if (tid < 64) {
    float s0 = 0.f, s1 = 0.f, sc = 0.f;
    for (int j = tid; j < V_; j += 64) { s0 += sh[j]; s1 += sh[V_ + j]; }
    for (int j = tid; j < GV; j += 64) sc += shc[j];
    for (int off = 32; off; off >>= 1) {
      s0 += __shfl_down(s0, off);
      s1 += __shfl_down(s1, off);
      sc += __shfl_down(sc, off);
    }
    if (tid == 0) {
      out2[0] = sc;                          // code_perplexity
      out2[1] = expf(-s0) + expf(-s1);       // prob_perplexity
    }
  }
}

extern "C" void kernel_launch(void* const* d_in, const int* in_sizes, int n_in,
                              void* d_out, int out_size, void* d_ws, size_t ws_size,
                              hipStream_t stream) {
  const float* x   = (const float*)d_in[0];  // (B,T,F)
  const float* w   = (const float*)d_in[1];  // (G*V, F)
  const float* b   = (const float*)d_in[2];  // (G*V,)
  const float* cb  = (const float*)d_in[3];  // (1, G*V, D)
  const float* gum = (const float*)d_in[4];  // (B*T, G, V)
  float* out = (float*)d_out;                // quantized (N*G*D) ++ [code_ppl, prob_ppl]
  float* ws  = (float*)d_ws;

  float* counts = ws + WS_COUNTS;
  float* avgp   = ws + WS_AVG;
  float* ent    = ws + WS_ENT;
  float* avgred = counts;  // reuse: counts is dead after k_stats (stream-ordered)

  hipMemsetAsync(counts, 0, (size_t)T_ * G_ * V_ * sizeof(float), stream);
  k_fused<<<NBLK, THREADS, 0, stream>>>(x, w, b, cb, gum, out, counts, avgp);
  k_stats<<<512 + GV / 4, 256, 0, stream>>>(counts, avgp, ent, avgred);
  k_final<<<1, GV, 0, stream>>>(avgred, ent, out + (size_t)N_ * G_ * D_);
}

// Round 8
// 444.754 us; speedup vs baseline: 2.0594x; 1.1025x over previous
//
#include <hip/hip_runtime.h>
#include <math.h>

// Problem constants (match reference)
#define B_   16
#define T_   1024
#define F_   512
#define G_   2
#define V_   320
#define D_   128
#define N_   (B_ * T_)      // 16384 tokens
#define GV   (G_ * V_)      // 640
#define EPS_ 1e-7f

// Kernel config
#define ROWS    32          // rows per block
#define THREADS 256         // 4 waves; wave wvx owns rows wvx*8..wvx*8+7
#define KC      16          // k-chunk staged in LDS
#define WSTRIDE 20          // padded LDS row stride (floats); 2-way-max bank aliasing (free)
#define NBLK    (N_ / ROWS) // 512 blocks -> 2 blocks/CU, grid fully resident
#define NCHUNK  (F_ / KC)   // 32

// Workspace layout (floats)
#define WS_AVG    0                   // NBLK*GV = 327680 floats
#define WS_A1     (NBLK * GV)         // hard-argmax ushort[T_*G_*B_] = 16384 floats
#define WS_TICKET (WS_A1 + 16384)     // 1 uint (memset to 0 each launch)

#define FMA4(a, xv, wv_)                                                       \
  a = fmaf(xv.x, wv_.x, a); a = fmaf(xv.y, wv_.y, a);                          \
  a = fmaf(xv.z, wv_.z, a); a = fmaf(xv.w, wv_.w, a);

// Fused: GEMM (x @ w^T + b) + softmax stats + argmaxes + codebook gather +
// last-block tail (code/prob perplexity). Inner loop holds ONE w float4 live
// at a time so peak live set (~118 regs) fits the allocator's preferred 128
// (R5-R7: any config needing >128 spilled; attributes to raise the cap were
// ignored). Last-block ticket pattern replaces counts histogram + 2 kernels.
__global__ __launch_bounds__(THREADS) void k_fused(
    const float* __restrict__ x, const float* __restrict__ w,
    const float* __restrict__ bias, const float* __restrict__ cb,
    const float* __restrict__ gum, float* __restrict__ out,
    float* __restrict__ avg_part, unsigned short* __restrict__ a1buf,
    unsigned int* __restrict__ ticket)
{
  __shared__ float lw[GV][WSTRIDE];    // 50 KB   w k-slab, padded
  __shared__ float lx[ROWS][WSTRIDE];  // 2.5 KB  x k-slab, padded
  __shared__ unsigned int sdone;
  const int tid = threadIdx.x;
  const int wvx = tid >> 6;   // wave / row-group 0..3
  const int ln  = tid & 63;
  const int blk = blockIdx.x;
  const int n0  = blk * ROWS;
  const int r0  = wvx * 8;

  float acc[G_][5][8];
#pragma unroll
  for (int g = 0; g < G_; ++g)
#pragma unroll
    for (int j = 0; j < 5; ++j)
#pragma unroll
      for (int r = 0; r < 8; ++r) acc[g][j][r] = 0.f;

  const float4* w4 = (const float4*)w;
  const float4* x4 = (const float4*)x;
  const int srow = tid >> 2, squad = tid & 3;  // staging map

  for (int c = 0; c < NCHUNK; ++c) {  // 32 chunks
    __syncthreads();
    // stage w k-slab: 640 rows x 16 k (10 float4 per thread), x: 32 x 16
#pragma unroll
    for (int it = 0; it < 10; ++it)
      *(float4*)&lw[srow + 64 * it][squad * 4] =
          w4[(size_t)(srow + 64 * it) * (F_ / 4) + c * 4 + squad];
    if (tid < ROWS * 4)
      *(float4*)&lx[srow][squad * 4] =
          x4[(size_t)(n0 + srow) * (F_ / 4) + c * 4 + squad];
    __syncthreads();

#pragma unroll
    for (int kk = 0; kk < 4; ++kk) {
      float4 xreg[8];
#pragma unroll
      for (int r = 0; r < 8; ++r)
        xreg[r] = *(const float4*)&lx[r0 + r][kk * 4];  // wave-uniform broadcast
#pragma unroll
      for (int g = 0; g < G_; ++g)
#pragma unroll
        for (int j = 0; j < 5; ++j) {
          const float4 wv4 = *(const float4*)&lw[g * V_ + 64 * j + ln][kk * 4];
#pragma unroll
          for (int r = 0; r < 8; ++r) { FMA4(acc[g][j][r], xreg[r], wv4); }
        }
    }
  }

  // ---- phase 2: per-row softmax / argmax / gather, all from registers ----
  float bs[G_][5];
#pragma unroll
  for (int g = 0; g < G_; ++g)
#pragma unroll
    for (int j = 0; j < 5; ++j) bs[g][j] = bias[g * V_ + 64 * j + ln];

  float racc[G_][5];
#pragma unroll
  for (int g = 0; g < G_; ++g)
#pragma unroll
    for (int j = 0; j < 5; ++j) racc[g][j] = 0.f;

#pragma unroll
  for (int r = 0; r < 8; ++r) {
    const int n = n0 + r0 + r;
#pragma unroll
    for (int g = 0; g < G_; ++g) {
      float L[5], GU[5];
#pragma unroll
      for (int j = 0; j < 5; ++j) {
        L[j]  = acc[g][j][r] + bs[g][j];
        GU[j] = gum[(size_t)n * GV + g * V_ + 64 * j + ln];
      }
      // local max/argmax (cols ascend with j -> first-occurrence tie-break)
      float m1 = L[0];         int a1 = ln;
      float m2 = L[0] + GU[0]; int a2 = ln;
#pragma unroll
      for (int j = 1; j < 5; ++j) {
        const int cix = 64 * j + ln;
        if (L[j] > m1) { m1 = L[j]; a1 = cix; }
        const float t2 = L[j] + GU[j];
        if (t2 > m2) { m2 = t2; a2 = cix; }
      }
      // wave reduce (prefer smaller index on exact ties)
      for (int off = 32; off; off >>= 1) {
        float om = __shfl_down(m1, off); int oa = __shfl_down(a1, off);
        if (om > m1 || (om == m1 && oa < a1)) { m1 = om; a1 = oa; }
        float om2 = __shfl_down(m2, off); int oa2 = __shfl_down(a2, off);
        if (om2 > m2 || (om2 == m2 && oa2 < a2)) { m2 = om2; a2 = oa2; }
      }
      m1 = __shfl(m1, 0); a1 = __shfl(a1, 0); a2 = __shfl(a2, 0);

      // softmax (no tau) for avg_probs
      float e[5], s = 0.f;
#pragma unroll
      for (int j = 0; j < 5; ++j) { e[j] = expf(L[j] - m1); s += e[j]; }
      for (int off = 32; off; off >>= 1) s += __shfl_down(s, off);
      s = __shfl(s, 0);
      const float inv = 1.0f / s;
#pragma unroll
      for (int j = 0; j < 5; ++j) racc[g][j] += e[j] * inv;

      if (ln == 0) {
        const int t = n & (T_ - 1), bidx = n >> 10;
        a1buf[(t * G_ + g) * B_ + bidx] = (unsigned short)a1;
      }
      // quantized[n, g*D : (g+1)*D] = codebook[g, a2, :]
      const float2* cbr = (const float2*)(cb + (size_t)(g * V_ + a2) * D_);
      float2* op = (float2*)(out + (size_t)n * (G_ * D_) + g * D_);
      op[ln] = cbr[ln];
    }
  }

  // ---- block-level avg_probs partial: reduce 4 wave-private copies ----
  __syncthreads();
  float* la = (float*)lw;  // [4][GV]: 10240 floats <= 640*20
#pragma unroll
  for (int g = 0; g < G_; ++g)
#pragma unroll
    for (int j = 0; j < 5; ++j)
      la[wvx * GV + g * V_ + 64 * j + ln] = racc[g][j];
  __syncthreads();
  for (int cix = tid; cix < GV; cix += THREADS) {
    float s = 0.f;
#pragma unroll
    for (int v = 0; v < 4; ++v) s += la[v * GV + cix];
    avg_part[(size_t)blk * GV + cix] = s;
  }

  // ---- ticket: last block to finish runs the stats tail ----
  __syncthreads();  // all stores of this block issued (barrier drains vmcnt)
  if (tid == 0) {
    __threadfence();                       // publish this XCD's stores
    sdone = atomicAdd(ticket, 1u);        // device-scope
  }
  __syncthreads();
  if (sdone != NBLK - 1) return;
  __threadfence();  // acquire side

  // ===== tail (one block, 256 threads) =====
  float* outs = out + (size_t)N_ * (G_ * D_);

  // (1) code perplexity: per (t,g), histogram of 16 batch argmaxes in regs
  float pplAcc = 0.f;
  for (int item = tid; item < T_ * G_; item += THREADS) {  // 8 iters, coalesced
    const uint4* p = (const uint4*)(a1buf + (size_t)item * B_);
    uint4 u0 = p[0], u1 = p[1];
    int idx[16];
    idx[0]=u0.x&0xffff; idx[1]=u0.x>>16; idx[2]=u0.y&0xffff; idx[3]=u0.y>>16;
    idx[4]=u0.z&0xffff; idx[5]=u0.z>>16; idx[6]=u0.w&0xffff; idx[7]=u0.w>>16;
    idx[8]=u1.x&0xffff; idx[9]=u1.x>>16; idx[10]=u1.y&0xffff; idx[11]=u1.y>>16;
    idx[12]=u1.z&0xffff; idx[13]=u1.z>>16; idx[14]=u1.w&0xffff; idx[15]=u1.w>>16;
    float H = 0.f;
#pragma unroll
    for (int b = 0; b < 16; ++b) {
      int cnt = 0;
#pragma unroll
      for (int b2 = 0; b2 < 16; ++b2) cnt += (idx[b] == idx[b2]) ? 1 : 0;
      H += logf((float)cnt * (1.0f / B_) + EPS_);
    }
    pplAcc += expf(-H * (1.0f / B_));
  }
  float* lxf = (float*)lx;   // 640-float scratch
  lxf[tid] = pplAcc;

  // (2) avg_probs column reduce + p*log(p+eps)
  float* sh = (float*)lw;    // 640-float scratch
  for (int cix = tid; cix < GV; cix += THREADS) {
    float s = 0.f;
    for (int b = 0; b < NBLK; ++b) s += avg_part[(size_t)b * GV + cix];
    const float pv = s * (1.0f / N_);
    sh[cix] = pv * logf(pv + EPS_);
  }
  __syncthreads();

  if (tid < 64) {
    float s0 = 0.f, s1 = 0.f, sc = 0.f;
    for (int j = tid; j < V_; j += 64) { s0 += sh[j]; s1 += sh[V_ + j]; }
#pragma unroll
    for (int v = 0; v < 4; ++v) sc += lxf[tid + 64 * v];
    for (int off = 32; off; off >>= 1) {
      s0 += __shfl_down(s0, off);
      s1 += __shfl_down(s1, off);
      sc += __shfl_down(sc, off);
    }
    if (tid == 0) {
      outs[0] = sc;                          // code_perplexity
      outs[1] = expf(-s0) + expf(-s1);       // prob_perplexity
    }
  }
}

extern "C" void kernel_launch(void* const* d_in, const int* in_sizes, int n_in,
                              void* d_out, int out_size, void* d_ws, size_t ws_size,
                              hipStream_t stream) {
  const float* x   = (const float*)d_in[0];  // (B,T,F)
  const float* w   = (const float*)d_in[1];  // (G*V, F)
  const float* b   = (const float*)d_in[2];  // (G*V,)
  const float* cb  = (const float*)d_in[3];  // (1, G*V, D)
  const float* gum = (const float*)d_in[4];  // (B*T, G, V)
  float* out = (float*)d_out;                // quantized (N*G*D) ++ [code_ppl, prob_ppl]
  float* ws  = (float*)d_ws;

  float* avgp = ws + WS_AVG;
  unsigned short* a1buf = (unsigned short*)(ws + WS_A1);
  unsigned int* ticket  = (unsigned int*)(ws + WS_TICKET);

  hipMemsetAsync(ticket, 0, sizeof(unsigned int), stream);
  k_fused<<<NBLK, THREADS, 0, stream>>>(x, w, b, cb, gum, out, avgp, a1buf, ticket);
}